// Round 5
// baseline (247.480 us; speedup 1.0000x reference)
//
#include <hip/hip_runtime.h>
#include <hip/hip_bf16.h>
#include <stdint.h>

// Problem constants
#define BATCH 64
#define CHN 3
#define HH 224
#define WW 224
#define PIX (HH * WW)          // 50176
#define NSEG 196
#define MAXP 400
#define KDIM (CHN * MAXP)      // 1200
#define DN 768

#define KP4 1216               // K in u32 hi/lo pairs per row (padded)
#define NTK 38                 // 1216 / 32 K-steps
#define MROWS (BATCH * NSEG)   // 12544

// chunking for stable rank assignment
#define CHSZ 512
#define NCH (PIX / CHSZ)       // 98

typedef short short8 __attribute__((ext_vector_type(8)));
typedef float f32x4 __attribute__((ext_vector_type(4)));
typedef unsigned int uint4v __attribute__((ext_vector_type(4)));

// K permutation: k = c*MAXP + r -> kappa = 3r + c (scatter writes one dwordx3
// per pixel). Applied to BOTH A and W; dot product invariant.

// pack fp32 -> (bf16_hi << 16) | bf16_lo  with hi = rn(v), lo = rn(v - hi)
// NOTE: as a bf16x2 little-endian word this is (elem0=lo, elem1=hi) — fed
// RAW to mfma_bf16 it contributes lo*lo' + hi*hi' at adjacent k-slots.
__device__ __forceinline__ uint32_t packhl(float v) {
    uint32_t x = __float_as_uint(v);
    uint32_t hi = (x + 0x7FFFu + ((x >> 16) & 1u)) >> 16;
    float r = v - __uint_as_float(hi << 16);
    uint32_t y = __float_as_uint(r);
    uint32_t lo = (y + 0x7FFFu + ((y >> 16) & 1u)) >> 16;
    return (hi << 16) | lo;
}

// ---------------------------------------------------------------------------
// Pass 1: per-chunk per-segment histogram
__global__ void k_hist(const int* __restrict__ seg, int* __restrict__ hist) {
    __shared__ int cnt[NSEG];
    int blk = blockIdx.x;
    int b = blk / NCH, ch = blk % NCH;
    int tid = threadIdx.x;
    if (tid < NSEG) cnt[tid] = 0;
    __syncthreads();
    int s = seg[(size_t)b * PIX + ch * CHSZ + tid];
    atomicAdd(&cnt[s], 1);
    __syncthreads();
    if (tid < NSEG) hist[(size_t)blk * NSEG + tid] = cnt[tid];
}

// ---------------------------------------------------------------------------
// Pass 2: exclusive prefix over the 98 chunks for each (b,s) — one wave per
// (b,s), shuffle scan (98 = 64 + 34). Totals go to counts[].
__global__ void k_scan(int* __restrict__ hist, int* __restrict__ counts) {
    int gw = blockIdx.x * 4 + (threadIdx.x >> 6);   // 0..12543
    int lane = threadIdx.x & 63;
    int b = gw / NSEG, s = gw - b * NSEG;
    size_t base = (size_t)b * NCH * NSEG + s;
    int v0 = hist[base + (size_t)lane * NSEG];
    int v1 = (lane < NCH - 64) ? hist[base + (size_t)(lane + 64) * NSEG] : 0;
    int p0 = v0, p1 = v1;
    #pragma unroll
    for (int d = 1; d < 64; d <<= 1) {
        int t0 = __shfl_up(p0, d);
        int t1 = __shfl_up(p1, d);
        if (lane >= d) { p0 += t0; p1 += t1; }
    }
    int tot0 = __shfl(p0, 63);
    hist[base + (size_t)lane * NSEG] = p0 - v0;                       // exclusive
    if (lane < NCH - 64) hist[base + (size_t)(lane + 64) * NSEG] = tot0 + p1 - v1;
    if (lane == NCH - 64 - 1) counts[gw] = tot0 + p1;                 // total
}

// ---------------------------------------------------------------------------
// Pass 2b: zero only the unwritten tail of each A row: [3*min(cnt,400), 1216).
__global__ void k_ztail(const int* __restrict__ counts, uint32_t* __restrict__ Apair) {
    int row = blockIdx.x * 4 + (threadIdx.x >> 6);
    int lane = threadIdx.x & 63;
    int cnt = counts[row];
    int start = 3 * min(cnt, MAXP);
    uint32_t* p = Apair + (size_t)row * KP4;
    for (int i = start + lane; i < KP4; i += 64) p[i] = 0u;
}

// ---------------------------------------------------------------------------
// Pass 3: stable rank via ballot-match + cross-wave LDS totals; scatter packed
// bf16 hi/lo pairs as one dwordx3 per pixel at kappa = 3r + c.
// blockIdx XCD-grouped by batch (6272 = 8*784) so each batch's ~1 MB Apair
// slab accumulates within one XCD's L2.
__global__ void k_scatter(const float* __restrict__ img,
                          const int* __restrict__ seg,
                          const int* __restrict__ offs,
                          uint32_t* __restrict__ Apair) {
    __shared__ int soff[NSEG];
    __shared__ int wcnt[8][NSEG];
    int blk0 = blockIdx.x;
    int wg = (blk0 & 7) * (BATCH * NCH / 8) + (blk0 >> 3);  // bijective, 784/XCD
    int b = wg / NCH, ch = wg % NCH;
    int tid = threadIdx.x;
    int lane = tid & 63, wid = tid >> 6;

    for (int i = tid; i < 8 * NSEG; i += CHSZ) ((int*)wcnt)[i] = 0;
    if (tid < NSEG) soff[tid] = offs[(size_t)wg * NSEG + tid];
    __syncthreads();

    int p = ch * CHSZ + tid;
    int sv = seg[(size_t)b * PIX + p];

    // ballot-based match_any over the 8 bits of sv (NSEG=196 < 256)
    uint64_t m = ~0ull;
    #pragma unroll
    for (int bit = 0; bit < 8; ++bit) {
        uint64_t bal = __ballot((sv >> bit) & 1);
        m &= ((sv >> bit) & 1) ? bal : ~bal;
    }
    int before = __popcll(m & ((1ull << lane) - 1ull));
    int first  = __builtin_ctzll(m);
    if (lane == first) wcnt[wid][sv] = __popcll(m);
    __syncthreads();

    int base = soff[sv];
    for (int w2 = 0; w2 < wid; ++w2) base += wcnt[w2][sv];  // wid wave-uniform
    int r = base + before;

    if (r < MAXP) {
        const float* ib = img + (size_t)b * CHN * PIX + p;
        uint32_t* dst = Apair + (size_t)(b * NSEG + sv) * KP4 + 3 * r;
        uint32_t v0 = packhl(ib[0]);
        uint32_t v1 = packhl(ib[PIX]);
        uint32_t v2 = packhl(ib[2 * PIX]);
        dst[0] = v0; dst[1] = v1; dst[2] = v2;
    }
}

// ---------------------------------------------------------------------------
// Pass 4: W [1200][768] fp32 -> Wt [768][KP4] packed bf16 hi/lo, transposed,
// with the kappa K-permutation.
__global__ void k_wprep(const float* __restrict__ W, uint32_t* __restrict__ Wt) {
    __shared__ float t[32][33];
    int kt = blockIdx.x, nt = blockIdx.y;
    int tid = threadIdx.x;
    int tx = tid & 31, ty = tid >> 5;  // 32 x 8
    #pragma unroll
    for (int i = 0; i < 4; ++i) {
        int k = kt * 32 + i * 8 + ty;
        int n = nt * 32 + tx;
        t[i * 8 + ty][tx] = (k < KDIM) ? W[(size_t)k * DN + n] : 0.0f;
    }
    __syncthreads();
    #pragma unroll
    for (int i = 0; i < 4; ++i) {
        int n = nt * 32 + i * 8 + ty;
        int k = kt * 32 + tx;
        int kap = (k < KDIM) ? 3 * (k % MAXP) + (k / MAXP) : k;
        Wt[(size_t)n * KP4 + kap] = packhl(t[tx][i * 8 + ty]);
    }
}

// ---------------------------------------------------------------------------
// Pass 5: pair-direct MFMA GEMM, exact 4-term split product in 2 passes:
//   pass1: mfma(A_raw,  B_raw ) = sum(hi*hi' + lo*lo')
//   pass2: mfma(A_raw, rot16(B)) = sum(hi*lo' + lo*hi')
// 128x128 tile, 512 threads (8 waves 2x4, wave tile 64x32), BK=32 pairs,
// double-buffered LDS via global_load_lds, XOR slot swizzle, XCD-grouped grid.
__device__ __forceinline__ void gld16(const void* g, void* l) {
    __builtin_amdgcn_global_load_lds(
        (const __attribute__((address_space(1))) unsigned int*)g,
        (__attribute__((address_space(3))) unsigned int*)l, 16, 0, 0);
}

#define NWG 588   // 98 bm * 6 bn
__global__ __launch_bounds__(512, 4) void k_gemm(const uint32_t* __restrict__ A,
                                                 const uint32_t* __restrict__ Bw,
                                                 const float* __restrict__ bias,
                                                 float* __restrict__ Co) {
    __shared__ uint32_t lds[2][2][128 * 32];   // [buf][A|B][row*32 + slotword]
    // bijective XCD-grouping swizzle (m204): q=73, rm=4
    int j = blockIdx.x;
    int xcd = j & 7, sl = j >> 3;
    const int q = NWG / 8, rm = NWG % 8;
    int wgid = (xcd < rm ? xcd * (q + 1) : rm * (q + 1) + (xcd - rm) * q) + sl;
    int bm = wgid / 6, bn = wgid % 6;

    int tid = threadIdx.x;
    int lane = tid & 63, w = tid >> 6;    // 8 waves
    int wm = w >> 2, wn = w & 3;          // 2 x 4; wave tile 64 rows x 32 cols
    int r15 = lane & 15, kb = lane >> 4;

    // staging: each thread loads 2x16B per matrix; rows w*8..w*8+7 (+64)
    int srow = w * 8 + (lane >> 3);
    int sslot = lane & 7;
    int ssw = sslot ^ (srow & 7);         // pre-swizzled source slot
    size_t aoff0 = (size_t)srow * KP4 + ssw * 4;
    size_t aoff1 = (size_t)(srow + 64) * KP4 + ssw * 4;  // (srow+64)&7 == srow&7

    const uint32_t* Ab = A + (size_t)(bm * 128) * KP4;
    const uint32_t* Bb = Bw + (size_t)(bn * 128) * KP4;

    f32x4 acc[4][2] = {};

#define STAGE(buf, kt) do {                                        \
    gld16(Ab + aoff0 + (size_t)(kt) * 32, &lds[buf][0][w * 256]);  \
    gld16(Ab + aoff1 + (size_t)(kt) * 32, &lds[buf][0][2048 + w * 256]); \
    gld16(Bb + aoff0 + (size_t)(kt) * 32, &lds[buf][1][w * 256]);  \
    gld16(Bb + aoff1 + (size_t)(kt) * 32, &lds[buf][1][2048 + w * 256]); \
} while (0)

    STAGE(0, 0);
    __syncthreads();

    int cur = 0;
    for (int kt = 0; kt < NTK; ++kt) {
        if (kt + 1 < NTK) STAGE(cur ^ 1, kt + 1);

        #pragma unroll
        for (int sg = 0; sg < 2; ++sg) {
            union { uint4v u; short8 s; } af[4];
            #pragma unroll
            for (int mi = 0; mi < 4; ++mi) {
                int row = wm * 64 + mi * 16 + r15;
                int slot = (sg * 4 + kb) ^ (row & 7);
                af[mi].u = *(const uint4v*)&lds[cur][0][row * 32 + slot * 4];
            }
            #pragma unroll
            for (int ni = 0; ni < 2; ++ni) {
                int row = wn * 32 + ni * 16 + r15;
                int slot = (sg * 4 + kb) ^ (row & 7);
                union { uint4v u; short8 s; } bf, bs;
                bf.u = *(const uint4v*)&lds[cur][1][row * 32 + slot * 4];
                bs.u.x = (bf.u.x >> 16) | (bf.u.x << 16);
                bs.u.y = (bf.u.y >> 16) | (bf.u.y << 16);
                bs.u.z = (bf.u.z >> 16) | (bf.u.z << 16);
                bs.u.w = (bf.u.w >> 16) | (bf.u.w << 16);
                #pragma unroll
                for (int mi = 0; mi < 4; ++mi) {
                    acc[mi][ni] = __builtin_amdgcn_mfma_f32_16x16x32_bf16(
                        af[mi].s, bf.s, acc[mi][ni], 0, 0, 0);
                    acc[mi][ni] = __builtin_amdgcn_mfma_f32_16x16x32_bf16(
                        af[mi].s, bs.s, acc[mi][ni], 0, 0, 0);
                }
            }
        }

        __syncthreads();
        cur ^= 1;
    }
#undef STAGE

    // C row = bm*128 + wm*64 + mi*16 + kb*4 + e; col = bn*128 + wn*32 + ni*16 + r15
    #pragma unroll
    for (int ni = 0; ni < 2; ++ni) {
        int col = bn * 128 + wn * 32 + ni * 16 + r15;
        float bv = bias[col];
        #pragma unroll
        for (int mi = 0; mi < 4; ++mi) {
            int rbase = bm * 128 + wm * 64 + mi * 16 + kb * 4;
            #pragma unroll
            for (int e = 0; e < 4; ++e)
                Co[(size_t)(rbase + e) * DN + col] = acc[mi][ni][e] + bv;
        }
    }
}

// ---------------------------------------------------------------------------
extern "C" void kernel_launch(void* const* d_in, const int* in_sizes, int n_in,
                              void* d_out, int out_size, void* d_ws, size_t ws_size,
                              hipStream_t stream) {
    const float* img = (const float*)d_in[0];
    const int*   seg = (const int*)d_in[1];
    const float* W   = (const float*)d_in[2];
    const float* bia = (const float*)d_in[3];
    float* out = (float*)d_out;

    const size_t APAIR_BYTES = (size_t)MROWS * KP4 * 4;            // 61,014,016
    const size_t HIST_BYTES  = (size_t)BATCH * NCH * NSEG * 4;     //  4,917,248
    uint32_t* Apair  = (uint32_t*)d_ws;
    int*      hist   = (int*)((char*)d_ws + APAIR_BYTES);
    int*      counts = (int*)((char*)d_ws + APAIR_BYTES + HIST_BYTES);
    // Wt overlaps hist: hist is dead after k_scatter; k_wprep runs after it.
    uint32_t* Wt     = (uint32_t*)hist;

    k_hist<<<BATCH * NCH, CHSZ, 0, stream>>>(seg, hist);
    k_scan<<<MROWS / 4, 256, 0, stream>>>(hist, counts);
    k_ztail<<<MROWS / 4, 256, 0, stream>>>(counts, Apair);
    k_scatter<<<BATCH * NCH, CHSZ, 0, stream>>>(img, seg, hist, Apair);
    k_wprep<<<dim3(NTK, DN / 32), 256, 0, stream>>>(W, Wt);

    k_gemm<<<NWG, 512, 0, stream>>>(Apair, Wt, bia, out);
}